// Round 5
// baseline (408.676 us; speedup 1.0000x reference)
//
#include <hip/hip_runtime.h>
#include <math.h>

#define Bc 2
#define Sc 2048
#define Dc 1024
#define Hc 16
#define HDc 64
#define NROWS 4096  // B*S

typedef __attribute__((ext_vector_type(8))) _Float16 f16x8;
typedef __attribute__((ext_vector_type(4))) _Float16 f16x4;
typedef __attribute__((ext_vector_type(4))) float f32x4;

// ---------------------------------------------------------------------------
// fp32 -> f16 hi + f16 lo  (x = hi + lo, lo = x - (float)hi)
// ---------------------------------------------------------------------------
__global__ __launch_bounds__(256)
void split_kernel(const float* __restrict__ src, _Float16* __restrict__ hi,
                  _Float16* __restrict__ lo, int n4)
{
  int i = blockIdx.x * 256 + threadIdx.x;
  if (i >= n4) return;
  float4 v = reinterpret_cast<const float4*>(src)[i];
  f16x4 h, l;
  h[0] = (_Float16)v.x; l[0] = (_Float16)(v.x - (float)h[0]);
  h[1] = (_Float16)v.y; l[1] = (_Float16)(v.y - (float)h[1]);
  h[2] = (_Float16)v.z; l[2] = (_Float16)(v.z - (float)h[2]);
  h[3] = (_Float16)v.w; l[3] = (_Float16)(v.w - (float)h[3]);
  reinterpret_cast<f16x4*>(hi)[i] = h;
  reinterpret_cast<f16x4*>(lo)[i] = l;
}

// ---------------------------------------------------------------------------
// Split-precision MFMA GEMM: C = (A@W^T + bias)*alpha via f16 hi/lo (3 MFMA).
//   mode 0: f16 head-split -> outb [B,H,S,HD]            (rows=B*S, cols=D)
//   mode 1: f16, rows are the o-index -> outb [B,H,HD,S] (rows=D, cols=B*S)
//           (bias indexed by ROW)
//   mode 2: fp32: out1 = val (gated); out0 = feats*val (out)
// ---------------------------------------------------------------------------
__global__ __launch_bounds__(256, 3)
void gemm_mfma(const _Float16* __restrict__ Ah, const _Float16* __restrict__ Al,
               const _Float16* __restrict__ Wh, const _Float16* __restrict__ Wl,
               const float* __restrict__ bias, float alpha,
               _Float16* __restrict__ outb,
               float* __restrict__ out0, float* __restrict__ out1,
               const float* __restrict__ feats, int mode)
{
  __shared__ _Float16 Ash[128][40];
  __shared__ _Float16 Asl[128][40];
  __shared__ _Float16 Wsh[128][40];
  __shared__ _Float16 Wsl[128][40];

  const int tid  = threadIdx.x;
  const int lane = tid & 63, wid = tid >> 6;
  const int l15  = lane & 15, l4 = lane >> 4;
  const int wr   = wid >> 1, wc = wid & 1;     // wave tile 64x64
  const int arow0 = blockIdx.x * 128;
  const int wrow0 = blockIdx.y * 128;

  f32x4 acc[4][4];
#pragma unroll
  for (int m = 0; m < 4; ++m)
#pragma unroll
    for (int n = 0; n < 4; ++n) acc[m][n] = f32x4{0.f, 0.f, 0.f, 0.f};

  for (int k0 = 0; k0 < Dc; k0 += 32) {
    __syncthreads();
#pragma unroll
    for (int p = 0; p < 2; ++p) {
      int e = tid + 256 * p;
      int r = e >> 2, c8 = (e & 3) * 8;
      size_t ao = (size_t)(arow0 + r) * Dc + k0 + c8;
      size_t wo = (size_t)(wrow0 + r) * Dc + k0 + c8;
      uint4 a0 = *reinterpret_cast<const uint4*>(Ah + ao);
      uint4 a1 = *reinterpret_cast<const uint4*>(Al + ao);
      uint4 w0 = *reinterpret_cast<const uint4*>(Wh + wo);
      uint4 w1 = *reinterpret_cast<const uint4*>(Wl + wo);
      *reinterpret_cast<uint4*>(&Ash[r][c8]) = a0;
      *reinterpret_cast<uint4*>(&Asl[r][c8]) = a1;
      *reinterpret_cast<uint4*>(&Wsh[r][c8]) = w0;
      *reinterpret_cast<uint4*>(&Wsl[r][c8]) = w1;
    }
    __syncthreads();

    f16x8 bh[4], bl[4];
#pragma unroll
    for (int n = 0; n < 4; ++n) {
      bh[n] = *reinterpret_cast<const f16x8*>(&Wsh[wc * 64 + n * 16 + l15][l4 * 8]);
      bl[n] = *reinterpret_cast<const f16x8*>(&Wsl[wc * 64 + n * 16 + l15][l4 * 8]);
    }
#pragma unroll
    for (int m = 0; m < 4; ++m) {
      f16x8 ah = *reinterpret_cast<const f16x8*>(&Ash[wr * 64 + m * 16 + l15][l4 * 8]);
      f16x8 al = *reinterpret_cast<const f16x8*>(&Asl[wr * 64 + m * 16 + l15][l4 * 8]);
#pragma unroll
      for (int n = 0; n < 4; ++n) {
        acc[m][n] = __builtin_amdgcn_mfma_f32_16x16x32_f16(ah, bh[n], acc[m][n], 0, 0, 0);
        acc[m][n] = __builtin_amdgcn_mfma_f32_16x16x32_f16(ah, bl[n], acc[m][n], 0, 0, 0);
        acc[m][n] = __builtin_amdgcn_mfma_f32_16x16x32_f16(al, bh[n], acc[m][n], 0, 0, 0);
      }
    }
  }

  // epilogue: C/D layout col = l15, row = l4*4 + reg
#pragma unroll
  for (int m = 0; m < 4; ++m) {
#pragma unroll
    for (int n = 0; n < 4; ++n) {
#pragma unroll
      for (int reg = 0; reg < 4; ++reg) {
        int r = arow0 + wr * 64 + m * 16 + l4 * 4 + reg;
        int c = wrow0 + wc * 64 + n * 16 + l15;
        float bval = (mode == 1) ? bias[r] : bias[c];
        float val = (acc[m][n][reg] + bval) * alpha;
        if (mode == 0) {
          int b = r >> 11, s = r & (Sc - 1), h = c >> 6, hd = c & 63;
          outb[(((size_t)b * Hc + h) * Sc + s) * HDc + hd] = (_Float16)val;
        } else if (mode == 1) {
          int h = r >> 6, hd = r & 63, b = c >> 11, s = c & (Sc - 1);
          outb[(((size_t)b * Hc + h) * HDc + hd) * Sc + s] = (_Float16)val;
        } else {
          out1[(size_t)r * Dc + c] = val;
          out0[(size_t)r * Dc + c] = feats[(size_t)r * Dc + c] * val;
        }
      }
    }
  }
}

// ---------------------------------------------------------------------------
// Flash attention, f16 MFMA. Block = 4 waves; wave owns 16 q-rows (QB=64).
// Defer-max softmax (THR=8) + row-sums via ones-MFMA: no cross-lane shuffles
// on the common path. K/V reg-staged prefetch (T14).
// ---------------------------------------------------------------------------
#define QB 64
#define KB 64
#define NT (Sc / KB)

__global__ __launch_bounds__(256)
void attn_mfma(const _Float16* __restrict__ q,
               const _Float16* __restrict__ k,
               const _Float16* __restrict__ vt,
               const float* __restrict__ mask,
               _Float16* __restrict__ ctxh, _Float16* __restrict__ ctxl)
{
  __shared__ _Float16 Ks[KB][72];
  __shared__ _Float16 Vs[HDc][72];
  __shared__ _Float16 Ps[4][16][72];

  const int tid  = threadIdx.x;
  const int lane = tid & 63;
  const int wave = tid >> 6;
  const int l15  = lane & 15;
  const int l4   = lane >> 4;

  const int nqb  = Sc / QB;            // 32
  const int head = blockIdx.x / nqb;   // b*H + h
  const int q0   = (blockIdx.x % nqb) * QB;
  const int b    = head / Hc;
  const int h    = head % Hc;

  const _Float16* qbase  = q  + ((size_t)head * Sc + q0 + wave * 16) * HDc;
  const _Float16* kbase  = k  + (size_t)head * Sc * HDc;
  const _Float16* vtbase = vt + (size_t)head * HDc * Sc;
  const float*    mbase  = mask + ((size_t)b * Sc + q0 + wave * 16) * Sc;

  const int sr  = tid >> 3;          // staging row 0..31 (+32 for p=1)
  const int sc8 = (tid & 7) * 8;     // staging col

  f16x8 qf[2];
#pragma unroll
  for (int f = 0; f < 2; ++f)
    qf[f] = *reinterpret_cast<const f16x8*>(
        qbase + (size_t)l15 * HDc + l4 * 8 + 32 * f);

  f16x8 ones;
#pragma unroll
  for (int i = 0; i < 8; ++i) ones[i] = (_Float16)1.0f;

  f32x4 O[4];
#pragma unroll
  for (int dt = 0; dt < 4; ++dt) O[dt] = f32x4{0.f, 0.f, 0.f, 0.f};
  float m_r[4], l_r[4];
#pragma unroll
  for (int r = 0; r < 4; ++r) { m_r[r] = -3e38f; l_r[r] = 0.f; }

  // prologue: stage tile 0 into regs
  uint4 kr[2], vr[2];
#pragma unroll
  for (int p = 0; p < 2; ++p) {
    int r = sr + 32 * p;
    kr[p] = *reinterpret_cast<const uint4*>(kbase + (size_t)r * HDc + sc8);
    vr[p] = *reinterpret_cast<const uint4*>(vtbase + (size_t)r * Sc + sc8);
  }

  for (int kt = 0; kt < NT; ++kt) {
    const int k0 = kt * KB;
    // write staged regs -> LDS
#pragma unroll
    for (int p = 0; p < 2; ++p) {
      int r = sr + 32 * p;
      *reinterpret_cast<uint4*>(&Ks[r][sc8]) = kr[p];
      *reinterpret_cast<uint4*>(&Vs[r][sc8]) = vr[p];
    }
    __syncthreads();
    // prefetch next tile into regs (hidden under compute)
    if (kt + 1 < NT) {
      const int k1 = k0 + KB;
#pragma unroll
      for (int p = 0; p < 2; ++p) {
        int r = sr + 32 * p;
        kr[p] = *reinterpret_cast<const uint4*>(kbase + (size_t)(k1 + r) * HDc + sc8);
        vr[p] = *reinterpret_cast<const uint4*>(vtbase + (size_t)r * Sc + k1 + sc8);
      }
    }

    // S = Q K^T
    f32x4 s[4];
    __builtin_amdgcn_s_setprio(1);
#pragma unroll
    for (int nt = 0; nt < 4; ++nt) {
      f32x4 acc = f32x4{0.f, 0.f, 0.f, 0.f};
      acc = __builtin_amdgcn_mfma_f32_16x16x32_f16(
          qf[0], *reinterpret_cast<const f16x8*>(&Ks[16 * nt + l15][l4 * 8]),
          acc, 0, 0, 0);
      acc = __builtin_amdgcn_mfma_f32_16x16x32_f16(
          qf[1], *reinterpret_cast<const f16x8*>(&Ks[16 * nt + l15][l4 * 8 + 32]),
          acc, 0, 0, 0);
      s[nt] = acc;
    }
    __builtin_amdgcn_s_setprio(0);

    // + mask (D-layout: row = l4*4+reg, col = l15 + 16*nt)
#pragma unroll
    for (int reg = 0; reg < 4; ++reg) {
      const float* mr = mbase + (size_t)(l4 * 4 + reg) * Sc + k0 + l15;
#pragma unroll
      for (int nt = 0; nt < 4; ++nt) s[nt][reg] += mr[16 * nt];
    }

    // defer-max online softmax: lane-local max only on common path
    float lm[4];
    bool safe = true;
#pragma unroll
    for (int reg = 0; reg < 4; ++reg) {
      lm[reg] = fmaxf(fmaxf(s[0][reg], s[1][reg]), fmaxf(s[2][reg], s[3][reg]));
      safe = safe && (lm[reg] - m_r[reg] <= 8.0f);
    }
    if (!__all(safe)) {
      // rare path: full 16-lane row reduce + rescale
#pragma unroll
      for (int reg = 0; reg < 4; ++reg) {
        float vm = lm[reg];
        vm = fmaxf(vm, __shfl_xor(vm, 1));
        vm = fmaxf(vm, __shfl_xor(vm, 2));
        vm = fmaxf(vm, __shfl_xor(vm, 4));
        vm = fmaxf(vm, __shfl_xor(vm, 8));
        float mn = fmaxf(m_r[reg], vm);
        float ccf = __expf(m_r[reg] - mn);
        m_r[reg] = mn;
        l_r[reg] *= ccf;
#pragma unroll
        for (int dt = 0; dt < 4; ++dt) O[dt][reg] *= ccf;
      }
    }

    // P = exp(s - m)  (bounded by e^8), store f16
#pragma unroll
    for (int reg = 0; reg < 4; ++reg) {
#pragma unroll
      for (int nt = 0; nt < 4; ++nt) {
        float p = __expf(s[nt][reg] - m_r[reg]);
        Ps[wave][l4 * 4 + reg][l15 + 16 * nt] = (_Float16)p;
      }
    }

    asm volatile("" ::: "memory");  // order Ps writes before reads (same wave)

    f16x8 pa0 = *reinterpret_cast<const f16x8*>(&Ps[wave][l15][l4 * 8]);
    f16x8 pa1 = *reinterpret_cast<const f16x8*>(&Ps[wave][l15][l4 * 8 + 32]);

    __builtin_amdgcn_s_setprio(1);
    // row sums via ones-MFMA: D[row][*] = sum_k P[row][k]
    f32x4 lacc = f32x4{0.f, 0.f, 0.f, 0.f};
    lacc = __builtin_amdgcn_mfma_f32_16x16x32_f16(pa0, ones, lacc, 0, 0, 0);
    lacc = __builtin_amdgcn_mfma_f32_16x16x32_f16(pa1, ones, lacc, 0, 0, 0);

    // O += P V
#pragma unroll
    for (int dt = 0; dt < 4; ++dt) {
      O[dt] = __builtin_amdgcn_mfma_f32_16x16x32_f16(
          pa0, *reinterpret_cast<const f16x8*>(&Vs[16 * dt + l15][l4 * 8]),
          O[dt], 0, 0, 0);
      O[dt] = __builtin_amdgcn_mfma_f32_16x16x32_f16(
          pa1, *reinterpret_cast<const f16x8*>(&Vs[16 * dt + l15][l4 * 8 + 32]),
          O[dt], 0, 0, 0);
    }
    __builtin_amdgcn_s_setprio(0);

#pragma unroll
    for (int reg = 0; reg < 4; ++reg) l_r[reg] += lacc[reg];

    __syncthreads();  // all LDS reads done before next iter's stores
  }

  float inv[4];
#pragma unroll
  for (int reg = 0; reg < 4; ++reg) inv[reg] = 1.0f / l_r[reg];
#pragma unroll
  for (int dt = 0; dt < 4; ++dt)
#pragma unroll
    for (int reg = 0; reg < 4; ++reg) {
      int row = q0 + wave * 16 + l4 * 4 + reg;
      size_t addr = ((size_t)b * Sc + row) * Dc + h * HDc + l15 + 16 * dt;
      float val = O[dt][reg] * inv[reg];
      _Float16 hh = (_Float16)val;
      ctxh[addr] = hh;
      ctxl[addr] = (_Float16)(val - (float)hh);
    }
}

// ---------------------------------------------------------------------------
extern "C" void kernel_launch(void* const* d_in, const int* in_sizes, int n_in,
                              void* d_out, int out_size, void* d_ws, size_t ws_size,
                              hipStream_t stream) {
  const float* feats = (const float*)d_in[0];
  const float* mask  = (const float*)d_in[1];
  const float* wq    = (const float*)d_in[2];
  const float* bq    = (const float*)d_in[3];
  const float* wk    = (const float*)d_in[4];
  const float* bk    = (const float*)d_in[5];
  const float* wv    = (const float*)d_in[6];
  const float* bv    = (const float*)d_in[7];
  const float* wo    = (const float*)d_in[8];
  const float* bo    = (const float*)d_in[9];

  char* ws = (char*)d_ws;
  const size_t MB = (size_t)1 << 20;
  _Float16* fh  = (_Float16*)(ws);             // 8 MB
  _Float16* fl  = (_Float16*)(ws + 8  * MB);   // 8 MB
  _Float16* wqh = (_Float16*)(ws + 16 * MB);
  _Float16* wql = (_Float16*)(ws + 18 * MB);
  _Float16* wkh = (_Float16*)(ws + 20 * MB);
  _Float16* wkl = (_Float16*)(ws + 22 * MB);
  _Float16* wvh = (_Float16*)(ws + 24 * MB);
  _Float16* wvl = (_Float16*)(ws + 26 * MB);
  _Float16* woh = (_Float16*)(ws + 28 * MB);
  _Float16* wol = (_Float16*)(ws + 30 * MB);
  _Float16* qb  = (_Float16*)(ws + 32 * MB);
  _Float16* kb  = (_Float16*)(ws + 40 * MB);
  _Float16* vtb = (_Float16*)(ws + 48 * MB);
  _Float16* ctxh = (_Float16*)(ws + 56 * MB);
  _Float16* ctxl = (_Float16*)(ws + 64 * MB);  // end: 72 MB

  float* out   = (float*)d_out;
  float* gated = out + 4194304;

  // precision splits
  split_kernel<<<4096, 256, 0, stream>>>(feats, fh, fl, 1048576);
  split_kernel<<<1024, 256, 0, stream>>>(wq, wqh, wql, 262144);
  split_kernel<<<1024, 256, 0, stream>>>(wk, wkh, wkl, 262144);
  split_kernel<<<1024, 256, 0, stream>>>(wv, wvh, wvl, 262144);
  split_kernel<<<1024, 256, 0, stream>>>(wo, woh, wol, 262144);

  dim3 gqk(NROWS / 128, Dc / 128);   // (32, 8)
  dim3 gvt(Dc / 128, NROWS / 128);   // (8, 32)
  gemm_mfma<<<gqk, 256, 0, stream>>>(fh, fl, wqh, wql, bq, 0.125f, qb,
                                     nullptr, nullptr, nullptr, 0);
  gemm_mfma<<<gqk, 256, 0, stream>>>(fh, fl, wkh, wkl, bk, 1.0f, kb,
                                     nullptr, nullptr, nullptr, 0);
  // V^T = wv @ feats^T  (rows = o-index, cols = token)
  gemm_mfma<<<gvt, 256, 0, stream>>>(wvh, wvl, fh, fl, bv, 1.0f, vtb,
                                     nullptr, nullptr, nullptr, 1);

  attn_mfma<<<Bc * Hc * (Sc / QB), 256, 0, stream>>>(qb, kb, vtb, mask, ctxh, ctxl);

  gemm_mfma<<<gqk, 256, 0, stream>>>(ctxh, ctxl, woh, wol, bo, 1.0f, nullptr,
                                     out, gated, feats, 2);
}

// Round 6
// 316.747 us; speedup vs baseline: 1.2902x; 1.2902x over previous
//
#include <hip/hip_runtime.h>
#include <math.h>

#define Bc 2
#define Sc 2048
#define Dc 1024
#define Hc 16
#define HDc 64
#define NROWS 4096  // B*S

typedef __attribute__((ext_vector_type(8))) _Float16 f16x8;
typedef __attribute__((ext_vector_type(4))) _Float16 f16x4;
typedef __attribute__((ext_vector_type(4))) float f32x4;

// ---------------------------------------------------------------------------
// fp32 -> f16 hi + f16 lo  (x = hi + lo, lo = x - (float)hi)
// ---------------------------------------------------------------------------
__global__ __launch_bounds__(256)
void split_kernel(const float* __restrict__ src, _Float16* __restrict__ hi,
                  _Float16* __restrict__ lo, int n4)
{
  int i = blockIdx.x * 256 + threadIdx.x;
  if (i >= n4) return;
  float4 v = reinterpret_cast<const float4*>(src)[i];
  f16x4 h, l;
  h[0] = (_Float16)v.x; l[0] = (_Float16)(v.x - (float)h[0]);
  h[1] = (_Float16)v.y; l[1] = (_Float16)(v.y - (float)h[1]);
  h[2] = (_Float16)v.z; l[2] = (_Float16)(v.z - (float)h[2]);
  h[3] = (_Float16)v.w; l[3] = (_Float16)(v.w - (float)h[3]);
  reinterpret_cast<f16x4*>(hi)[i] = h;
  reinterpret_cast<f16x4*>(lo)[i] = l;
}

// ---------------------------------------------------------------------------
// Split-precision MFMA GEMM: C = (A@W^T + bias)*alpha via f16 hi/lo (3 MFMA).
//   mode 0: f16 head-split -> outb [B,H,S,HD]            (rows=B*S, cols=D)
//   mode 1: f16, rows are the o-index -> outb [B,H,HD,S] (rows=D, cols=B*S)
//           (bias indexed by ROW)
//   mode 2: fp32: out1 = val (gated); out0 = feats*val (out)
// ---------------------------------------------------------------------------
__global__ __launch_bounds__(256, 3)
void gemm_mfma(const _Float16* __restrict__ Ah, const _Float16* __restrict__ Al,
               const _Float16* __restrict__ Wh, const _Float16* __restrict__ Wl,
               const float* __restrict__ bias, float alpha,
               _Float16* __restrict__ outb,
               float* __restrict__ out0, float* __restrict__ out1,
               const float* __restrict__ feats, int mode)
{
  __shared__ _Float16 Ash[128][40];
  __shared__ _Float16 Asl[128][40];
  __shared__ _Float16 Wsh[128][40];
  __shared__ _Float16 Wsl[128][40];

  const int tid  = threadIdx.x;
  const int lane = tid & 63, wid = tid >> 6;
  const int l15  = lane & 15, l4 = lane >> 4;
  const int wr   = wid >> 1, wc = wid & 1;     // wave tile 64x64
  const int arow0 = blockIdx.x * 128;
  const int wrow0 = blockIdx.y * 128;

  f32x4 acc[4][4];
#pragma unroll
  for (int m = 0; m < 4; ++m)
#pragma unroll
    for (int n = 0; n < 4; ++n) acc[m][n] = f32x4{0.f, 0.f, 0.f, 0.f};

  for (int k0 = 0; k0 < Dc; k0 += 32) {
    __syncthreads();
#pragma unroll
    for (int p = 0; p < 2; ++p) {
      int e = tid + 256 * p;
      int r = e >> 2, c8 = (e & 3) * 8;
      size_t ao = (size_t)(arow0 + r) * Dc + k0 + c8;
      size_t wo = (size_t)(wrow0 + r) * Dc + k0 + c8;
      uint4 a0 = *reinterpret_cast<const uint4*>(Ah + ao);
      uint4 a1 = *reinterpret_cast<const uint4*>(Al + ao);
      uint4 w0 = *reinterpret_cast<const uint4*>(Wh + wo);
      uint4 w1 = *reinterpret_cast<const uint4*>(Wl + wo);
      *reinterpret_cast<uint4*>(&Ash[r][c8]) = a0;
      *reinterpret_cast<uint4*>(&Asl[r][c8]) = a1;
      *reinterpret_cast<uint4*>(&Wsh[r][c8]) = w0;
      *reinterpret_cast<uint4*>(&Wsl[r][c8]) = w1;
    }
    __syncthreads();

    f16x8 bh[4], bl[4];
#pragma unroll
    for (int n = 0; n < 4; ++n) {
      bh[n] = *reinterpret_cast<const f16x8*>(&Wsh[wc * 64 + n * 16 + l15][l4 * 8]);
      bl[n] = *reinterpret_cast<const f16x8*>(&Wsl[wc * 64 + n * 16 + l15][l4 * 8]);
    }
#pragma unroll
    for (int m = 0; m < 4; ++m) {
      f16x8 ah = *reinterpret_cast<const f16x8*>(&Ash[wr * 64 + m * 16 + l15][l4 * 8]);
      f16x8 al = *reinterpret_cast<const f16x8*>(&Asl[wr * 64 + m * 16 + l15][l4 * 8]);
#pragma unroll
      for (int n = 0; n < 4; ++n) {
        acc[m][n] = __builtin_amdgcn_mfma_f32_16x16x32_f16(ah, bh[n], acc[m][n], 0, 0, 0);
        acc[m][n] = __builtin_amdgcn_mfma_f32_16x16x32_f16(ah, bl[n], acc[m][n], 0, 0, 0);
        acc[m][n] = __builtin_amdgcn_mfma_f32_16x16x32_f16(al, bh[n], acc[m][n], 0, 0, 0);
      }
    }
  }

  // epilogue: C/D layout col = l15, row = l4*4 + reg
#pragma unroll
  for (int m = 0; m < 4; ++m) {
#pragma unroll
    for (int n = 0; n < 4; ++n) {
#pragma unroll
      for (int reg = 0; reg < 4; ++reg) {
        int r = arow0 + wr * 64 + m * 16 + l4 * 4 + reg;
        int c = wrow0 + wc * 64 + n * 16 + l15;
        float bval = (mode == 1) ? bias[r] : bias[c];
        float val = (acc[m][n][reg] + bval) * alpha;
        if (mode == 0) {
          int b = r >> 11, s = r & (Sc - 1), h = c >> 6, hd = c & 63;
          outb[(((size_t)b * Hc + h) * Sc + s) * HDc + hd] = (_Float16)val;
        } else if (mode == 1) {
          int h = r >> 6, hd = r & 63, b = c >> 11, s = c & (Sc - 1);
          outb[(((size_t)b * Hc + h) * HDc + hd) * Sc + s] = (_Float16)val;
        } else {
          out1[(size_t)r * Dc + c] = val;
          out0[(size_t)r * Dc + c] = feats[(size_t)r * Dc + c] * val;
        }
      }
    }
  }
}

// ---------------------------------------------------------------------------
// Flash attention, f16 MFMA. Block = 4 waves; wave owns 16 q-rows (QB=64).
// Direct global->LDS staging (round-4 proven). Defer-max softmax (THR=8) +
// row-sums via ones-MFMA: no cross-lane shuffles on the common path.
// ---------------------------------------------------------------------------
#define QB 64
#define KB 64
#define NT (Sc / KB)

__global__ __launch_bounds__(256)
void attn_mfma(const _Float16* __restrict__ q,
               const _Float16* __restrict__ k,
               const _Float16* __restrict__ vt,
               const float* __restrict__ mask,
               _Float16* __restrict__ ctxh, _Float16* __restrict__ ctxl)
{
  __shared__ _Float16 Ks[KB][72];
  __shared__ _Float16 Vs[HDc][72];
  __shared__ _Float16 Ps[4][16][72];

  const int tid  = threadIdx.x;
  const int lane = tid & 63;
  const int wave = tid >> 6;
  const int l15  = lane & 15;
  const int l4   = lane >> 4;

  const int nqb  = Sc / QB;            // 32
  const int head = blockIdx.x / nqb;   // b*H + h
  const int q0   = (blockIdx.x % nqb) * QB;
  const int b    = head / Hc;
  const int h    = head % Hc;

  const _Float16* qbase  = q  + ((size_t)head * Sc + q0 + wave * 16) * HDc;
  const _Float16* kbase  = k  + (size_t)head * Sc * HDc;
  const _Float16* vtbase = vt + (size_t)head * HDc * Sc;
  const float*    mbase  = mask + ((size_t)b * Sc + q0 + wave * 16) * Sc;

  f16x8 qf[2];
#pragma unroll
  for (int f = 0; f < 2; ++f)
    qf[f] = *reinterpret_cast<const f16x8*>(
        qbase + (size_t)l15 * HDc + l4 * 8 + 32 * f);

  f16x8 ones;
#pragma unroll
  for (int i = 0; i < 8; ++i) ones[i] = (_Float16)1.0f;

  f32x4 O[4];
#pragma unroll
  for (int dt = 0; dt < 4; ++dt) O[dt] = f32x4{0.f, 0.f, 0.f, 0.f};
  float m_r[4], l_r[4];
#pragma unroll
  for (int r = 0; r < 4; ++r) { m_r[r] = -3e38f; l_r[r] = 0.f; }

  for (int kt = 0; kt < NT; ++kt) {
    const int k0 = kt * KB;
    __syncthreads();  // protect Ks/Vs from previous iteration's readers
    // stage K tile [KB][64] and V^T tile [64][KB] (16B chunks, direct)
#pragma unroll
    for (int p = 0; p < 2; ++p) {
      int c = tid + 256 * p;
      int r = c >> 3, col = (c & 7) * 8;
      uint4 kd = *reinterpret_cast<const uint4*>(
          kbase + (size_t)(k0 + r) * HDc + col);
      *reinterpret_cast<uint4*>(&Ks[r][col]) = kd;
      uint4 vd = *reinterpret_cast<const uint4*>(
          vtbase + (size_t)r * Sc + k0 + col);
      *reinterpret_cast<uint4*>(&Vs[r][col]) = vd;
    }
    __syncthreads();

    // S = Q K^T
    f32x4 s[4];
    __builtin_amdgcn_s_setprio(1);
#pragma unroll
    for (int nt = 0; nt < 4; ++nt) {
      f32x4 acc = f32x4{0.f, 0.f, 0.f, 0.f};
      acc = __builtin_amdgcn_mfma_f32_16x16x32_f16(
          qf[0], *reinterpret_cast<const f16x8*>(&Ks[16 * nt + l15][l4 * 8]),
          acc, 0, 0, 0);
      acc = __builtin_amdgcn_mfma_f32_16x16x32_f16(
          qf[1], *reinterpret_cast<const f16x8*>(&Ks[16 * nt + l15][l4 * 8 + 32]),
          acc, 0, 0, 0);
      s[nt] = acc;
    }
    __builtin_amdgcn_s_setprio(0);

    // + mask (D-layout: row = l4*4+reg, col = l15 + 16*nt)
#pragma unroll
    for (int reg = 0; reg < 4; ++reg) {
      const float* mr = mbase + (size_t)(l4 * 4 + reg) * Sc + k0 + l15;
#pragma unroll
      for (int nt = 0; nt < 4; ++nt) s[nt][reg] += mr[16 * nt];
    }

    // defer-max online softmax: lane-local max only on common path
    float lm[4];
    bool safe = true;
#pragma unroll
    for (int reg = 0; reg < 4; ++reg) {
      lm[reg] = fmaxf(fmaxf(s[0][reg], s[1][reg]), fmaxf(s[2][reg], s[3][reg]));
      safe = safe && (lm[reg] - m_r[reg] <= 8.0f);
    }
    if (!__all(safe)) {
      // rare path: full 16-lane row reduce + rescale
#pragma unroll
      for (int reg = 0; reg < 4; ++reg) {
        float vm = lm[reg];
        vm = fmaxf(vm, __shfl_xor(vm, 1));
        vm = fmaxf(vm, __shfl_xor(vm, 2));
        vm = fmaxf(vm, __shfl_xor(vm, 4));
        vm = fmaxf(vm, __shfl_xor(vm, 8));
        float mn = fmaxf(m_r[reg], vm);
        float ccf = __expf(m_r[reg] - mn);
        m_r[reg] = mn;
        l_r[reg] *= ccf;
#pragma unroll
        for (int dt = 0; dt < 4; ++dt) O[dt][reg] *= ccf;
      }
    }

    // P = exp(s - m)  (bounded by e^8), store f16
#pragma unroll
    for (int reg = 0; reg < 4; ++reg) {
#pragma unroll
      for (int nt = 0; nt < 4; ++nt) {
        float p = __expf(s[nt][reg] - m_r[reg]);
        Ps[wave][l4 * 4 + reg][l15 + 16 * nt] = (_Float16)p;
      }
    }

    asm volatile("" ::: "memory");  // order Ps writes before reads (same wave)

    f16x8 pa0 = *reinterpret_cast<const f16x8*>(&Ps[wave][l15][l4 * 8]);
    f16x8 pa1 = *reinterpret_cast<const f16x8*>(&Ps[wave][l15][l4 * 8 + 32]);

    __builtin_amdgcn_s_setprio(1);
    // row sums via ones-MFMA: D[row][*] = sum_k P[row][k]
    f32x4 lacc = f32x4{0.f, 0.f, 0.f, 0.f};
    lacc = __builtin_amdgcn_mfma_f32_16x16x32_f16(pa0, ones, lacc, 0, 0, 0);
    lacc = __builtin_amdgcn_mfma_f32_16x16x32_f16(pa1, ones, lacc, 0, 0, 0);

    // O += P V
#pragma unroll
    for (int dt = 0; dt < 4; ++dt) {
      O[dt] = __builtin_amdgcn_mfma_f32_16x16x32_f16(
          pa0, *reinterpret_cast<const f16x8*>(&Vs[16 * dt + l15][l4 * 8]),
          O[dt], 0, 0, 0);
      O[dt] = __builtin_amdgcn_mfma_f32_16x16x32_f16(
          pa1, *reinterpret_cast<const f16x8*>(&Vs[16 * dt + l15][l4 * 8 + 32]),
          O[dt], 0, 0, 0);
    }
    __builtin_amdgcn_s_setprio(0);

#pragma unroll
    for (int reg = 0; reg < 4; ++reg) l_r[reg] += lacc[reg];
  }

  float inv[4];
#pragma unroll
  for (int reg = 0; reg < 4; ++reg) inv[reg] = 1.0f / l_r[reg];
#pragma unroll
  for (int dt = 0; dt < 4; ++dt)
#pragma unroll
    for (int reg = 0; reg < 4; ++reg) {
      int row = q0 + wave * 16 + l4 * 4 + reg;
      size_t addr = ((size_t)b * Sc + row) * Dc + h * HDc + l15 + 16 * dt;
      float val = O[dt][reg] * inv[reg];
      _Float16 hh = (_Float16)val;
      ctxh[addr] = hh;
      ctxl[addr] = (_Float16)(val - (float)hh);
    }
}

// ---------------------------------------------------------------------------
extern "C" void kernel_launch(void* const* d_in, const int* in_sizes, int n_in,
                              void* d_out, int out_size, void* d_ws, size_t ws_size,
                              hipStream_t stream) {
  const float* feats = (const float*)d_in[0];
  const float* mask  = (const float*)d_in[1];
  const float* wq    = (const float*)d_in[2];
  const float* bq    = (const float*)d_in[3];
  const float* wk    = (const float*)d_in[4];
  const float* bk    = (const float*)d_in[5];
  const float* wv    = (const float*)d_in[6];
  const float* bv    = (const float*)d_in[7];
  const float* wo    = (const float*)d_in[8];
  const float* bo    = (const float*)d_in[9];

  char* ws = (char*)d_ws;
  const size_t MB = (size_t)1 << 20;
  _Float16* fh  = (_Float16*)(ws);             // 8 MB
  _Float16* fl  = (_Float16*)(ws + 8  * MB);   // 8 MB
  _Float16* wqh = (_Float16*)(ws + 16 * MB);
  _Float16* wql = (_Float16*)(ws + 18 * MB);
  _Float16* wkh = (_Float16*)(ws + 20 * MB);
  _Float16* wkl = (_Float16*)(ws + 22 * MB);
  _Float16* wvh = (_Float16*)(ws + 24 * MB);
  _Float16* wvl = (_Float16*)(ws + 26 * MB);
  _Float16* woh = (_Float16*)(ws + 28 * MB);
  _Float16* wol = (_Float16*)(ws + 30 * MB);
  _Float16* qb  = (_Float16*)(ws + 32 * MB);
  _Float16* kb  = (_Float16*)(ws + 40 * MB);
  _Float16* vtb = (_Float16*)(ws + 48 * MB);
  _Float16* ctxh = (_Float16*)(ws + 56 * MB);
  _Float16* ctxl = (_Float16*)(ws + 64 * MB);  // end: 72 MB

  float* out   = (float*)d_out;
  float* gated = out + 4194304;

  // precision splits
  split_kernel<<<4096, 256, 0, stream>>>(feats, fh, fl, 1048576);
  split_kernel<<<1024, 256, 0, stream>>>(wq, wqh, wql, 262144);
  split_kernel<<<1024, 256, 0, stream>>>(wk, wkh, wkl, 262144);
  split_kernel<<<1024, 256, 0, stream>>>(wv, wvh, wvl, 262144);
  split_kernel<<<1024, 256, 0, stream>>>(wo, woh, wol, 262144);

  dim3 gqk(NROWS / 128, Dc / 128);   // (32, 8)
  dim3 gvt(Dc / 128, NROWS / 128);   // (8, 32)
  gemm_mfma<<<gqk, 256, 0, stream>>>(fh, fl, wqh, wql, bq, 0.125f, qb,
                                     nullptr, nullptr, nullptr, 0);
  gemm_mfma<<<gqk, 256, 0, stream>>>(fh, fl, wkh, wkl, bk, 1.0f, kb,
                                     nullptr, nullptr, nullptr, 0);
  // V^T = wv @ feats^T  (rows = o-index, cols = token)
  gemm_mfma<<<gvt, 256, 0, stream>>>(wvh, wvl, fh, fl, bv, 1.0f, vtb,
                                     nullptr, nullptr, nullptr, 1);

  attn_mfma<<<Bc * Hc * (Sc / QB), 256, 0, stream>>>(qb, kb, vtb, mask, ctxh, ctxl);

  gemm_mfma<<<gqk, 256, 0, stream>>>(ctxh, ctxl, woh, wol, bo, 1.0f, nullptr,
                                     out, gated, feats, 2);
}